// Round 1
// baseline (377.012 us; speedup 1.0000x reference)
//
#include <hip/hip_runtime.h>

#define D 64
#define K 1024
#define HW_ 1024      // 32*32
#define NVEC 65536    // 64 * 32 * 32

// ---------------------------------------------------------------------------
// Kernel 0: half squared norms of codebook rows.  ws[0..K) = 0.5*||e_k||^2
// ---------------------------------------------------------------------------
__global__ __launch_bounds__(256) void vq_norms(const float* __restrict__ emb,
                                                float* __restrict__ norms) {
    int k = blockIdx.x * 256 + threadIdx.x;
    if (k >= K) return;
    const float4* e4 = reinterpret_cast<const float4*>(emb + k * D);
    float s = 0.f;
#pragma unroll
    for (int i = 0; i < D / 4; ++i) {
        float4 v = e4[i];
        s = fmaf(v.x, v.x, s);
        s = fmaf(v.y, v.y, s);
        s = fmaf(v.z, v.z, s);
        s = fmaf(v.w, v.w, s);
    }
    norms[k] = 0.5f * s;
}

// ---------------------------------------------------------------------------
// Kernel 1: main VQ. One thread per spatial vector. z kept in 64 VGPRs.
// k-loop reads codebook at wave-uniform addresses -> scalar loads (SGPR
// broadcast), v_fmac with SGPR operand. argmax(z.e - 0.5||e||^2).
// ---------------------------------------------------------------------------
__global__ __launch_bounds__(256) void vq_main(const float* __restrict__ z,
                                               const float* __restrict__ emb,
                                               const float* __restrict__ norms,
                                               float* __restrict__ out,
                                               float* __restrict__ partials) {
    const int vid = blockIdx.x * 256 + threadIdx.x;  // 0..65535
    const int b  = vid >> 10;          // vid / (H*W)
    const int hw = vid & (HW_ - 1);

    const float* zb = z + (size_t)b * (D * HW_) + hw;   // z[b][d][hw], stride HW_ per d
    float zv[D];
#pragma unroll
    for (int d = 0; d < D; ++d) zv[d] = zb[d * HW_];    // coalesced across lanes

    float best = -1e30f;
    int   bidx = 0;
    for (int k = 0; k < K; ++k) {
        const float* ek = emb + k * D;                  // wave-uniform address
        float a0 = 0.f, a1 = 0.f, a2 = 0.f, a3 = 0.f;
#pragma unroll
        for (int d = 0; d < D; d += 4) {
            a0 = fmaf(zv[d + 0], ek[d + 0], a0);
            a1 = fmaf(zv[d + 1], ek[d + 1], a1);
            a2 = fmaf(zv[d + 2], ek[d + 2], a2);
            a3 = fmaf(zv[d + 3], ek[d + 3], a3);
        }
        float t = (a0 + a1) + (a2 + a3) - norms[k];
        if (t > best) { best = t; bidx = k; }           // strict > : first occurrence
    }

    // Epilogue: gather chosen code, write output [B, D, H, W], accumulate SSE.
    const float4* eb4 = reinterpret_cast<const float4*>(emb + bidx * D);
    float* ob = out + (size_t)b * (D * HW_) + hw;
    float sse = 0.f;
#pragma unroll
    for (int i = 0; i < D / 4; ++i) {
        float4 q = eb4[i];                              // L2-resident gather
        const int d = i * 4;
        ob[(d + 0) * HW_] = q.x;
        ob[(d + 1) * HW_] = q.y;
        ob[(d + 2) * HW_] = q.z;
        ob[(d + 3) * HW_] = q.w;
        float dx = q.x - zv[d + 0]; sse = fmaf(dx, dx, sse);
        float dy = q.y - zv[d + 1]; sse = fmaf(dy, dy, sse);
        float dz = q.z - zv[d + 2]; sse = fmaf(dz, dz, sse);
        float dw = q.w - zv[d + 3]; sse = fmaf(dw, dw, sse);
    }

    __shared__ float red[256];
    red[threadIdx.x] = sse;
    __syncthreads();
#pragma unroll
    for (int s = 128; s > 0; s >>= 1) {
        if (threadIdx.x < s) red[threadIdx.x] += red[threadIdx.x + s];
        __syncthreads();
    }
    if (threadIdx.x == 0) partials[blockIdx.x] = red[0];
}

// ---------------------------------------------------------------------------
// Kernel 2: reduce 256 block partials -> loss scalar at d_out[NVEC*D].
// loss = 1.25 * SSE / (NVEC*D)   (commitment 0.25*m + codebook m = 1.25*m)
// ---------------------------------------------------------------------------
__global__ __launch_bounds__(256) void vq_loss(const float* __restrict__ partials,
                                               float* __restrict__ loss_out) {
    __shared__ float red[256];
    red[threadIdx.x] = partials[threadIdx.x];
    __syncthreads();
#pragma unroll
    for (int s = 128; s > 0; s >>= 1) {
        if (threadIdx.x < s) red[threadIdx.x] += red[threadIdx.x + s];
        __syncthreads();
    }
    if (threadIdx.x == 0)
        loss_out[0] = 1.25f * red[0] * (1.0f / (float)(NVEC * D));
}

extern "C" void kernel_launch(void* const* d_in, const int* in_sizes, int n_in,
                              void* d_out, int out_size, void* d_ws, size_t ws_size,
                              hipStream_t stream) {
    const float* z   = (const float*)d_in[0];   // [64, 64, 32, 32]
    const float* emb = (const float*)d_in[1];   // [1024, 64]
    float* out = (float*)d_out;                 // 4194304 quantized + 1 loss

    float* norms    = (float*)d_ws;             // K floats
    float* partials = norms + K;                // 256 floats

    vq_norms<<<K / 256, 256, 0, stream>>>(emb, norms);
    vq_main<<<NVEC / 256, 256, 0, stream>>>(z, emb, norms, out, partials);
    vq_loss<<<1, 256, 0, stream>>>(partials, out + (size_t)NVEC * D);
}

// Round 2
// 34.060 us; speedup vs baseline: 11.0692x; 11.0692x over previous
//
#include <hip/hip_runtime.h>

#define D 64
#define K 1024
#define NVEC 65536
#define MB 128            // vectors per block
#define NBLK (NVEC / MB)  // 512
#define WAVES 4
#define KPW (K / WAVES)   // 256 codes per wave
#define TILES (KPW / 16)  // 16

typedef __attribute__((ext_vector_type(8))) short bf16x8;
typedef __attribute__((ext_vector_type(4))) float f32x4;

__device__ inline unsigned short f2bf(float f) {
    unsigned u = __builtin_bit_cast(unsigned, f);
    return (unsigned short)((u + 0x7FFFu + ((u >> 16) & 1u)) >> 16);  // RNE
}

// ---------------------------------------------------------------------------
// Prep: codebook f32 -> bf16 (for MFMA A-frags) + exact f32 half-norms.
// ---------------------------------------------------------------------------
__global__ __launch_bounds__(256) void vq_prep(const float* __restrict__ emb,
                                               unsigned short* __restrict__ ebf,
                                               float* __restrict__ hn) {
    const int k = blockIdx.x * 256 + threadIdx.x;   // 0..1023
    const float4* e4 = reinterpret_cast<const float4*>(emb + (size_t)k * D);
    ushort4* o4 = reinterpret_cast<ushort4*>(ebf + (size_t)k * D);
    float s = 0.f;
#pragma unroll
    for (int i = 0; i < D / 4; ++i) {
        float4 v = e4[i];
        s = fmaf(v.x, v.x, s); s = fmaf(v.y, v.y, s);
        s = fmaf(v.z, v.z, s); s = fmaf(v.w, v.w, s);
        ushort4 b; b.x = f2bf(v.x); b.y = f2bf(v.y); b.z = f2bf(v.z); b.w = f2bf(v.w);
        o4[i] = b;
    }
    hn[k] = 0.5f * s;
}

// ---------------------------------------------------------------------------
// Main: MFMA distance GEMM + argmax + gather/write + loss partials.
// Block: 256 thr (4 waves), 128 vectors. Wave w owns codes [w*256, w*256+256).
// ---------------------------------------------------------------------------
__global__ __launch_bounds__(256) void vq_mfma(const float* __restrict__ z,
                                               const float* __restrict__ emb,
                                               const unsigned short* __restrict__ ebf,
                                               const float* __restrict__ hn,
                                               float* __restrict__ out,
                                               float* __restrict__ pT,
                                               float* __restrict__ pZ) {
    __shared__ __align__(16) char zl[MB * 128];   // 16 KB: bf16 z-tile [v][d], XOR-swizzled
    __shared__ float wv_t[WAVES * MB];
    __shared__ int   wv_i[WAVES * MB];
    __shared__ int   fin_i[MB];
    __shared__ float red[256];

    const int tid = threadIdx.x;
    const int blk = blockIdx.x;
    const int b   = blk >> 3;             // batch
    const int hw0 = (blk & 7) * MB;       // first spatial pos of tile
    const float* zb = z + (size_t)b * (D * 1024) + hw0;   // zb[d*1024 + v]

    // ---- stage z tile: global f32 [d][v] -> LDS bf16 [v][d] (swizzled); f32 sum(z^2)
    float zacc = 0.f;
#pragma unroll
    for (int it = 0; it < 2; ++it) {
        const int item = it * 256 + tid;      // 0..511
        const int v4 = item & 31;             // 4-vector group
        const int d4 = item >> 5;             // 4-d group
        float4 r[4];
#pragma unroll
        for (int i = 0; i < 4; ++i)
            r[i] = *reinterpret_cast<const float4*>(zb + (size_t)(d4 * 4 + i) * 1024 + v4 * 4);
        const float* rf = reinterpret_cast<const float*>(r);
#pragma unroll
        for (int n = 0; n < 16; ++n) zacc = fmaf(rf[n], rf[n], zacc);
#pragma unroll
        for (int j = 0; j < 4; ++j) {         // vector v gets d = d4*4 + i
            const int v = v4 * 4 + j;
            ushort4 pk;
            pk.x = f2bf(rf[0 * 4 + j]); pk.y = f2bf(rf[1 * 4 + j]);
            pk.z = f2bf(rf[2 * 4 + j]); pk.w = f2bf(rf[3 * 4 + j]);
            const int byte = v * 128 + ((d4 * 8) ^ ((v & 7) << 4));
            *reinterpret_cast<ushort4*>(zl + byte) = pk;
        }
    }
    __syncthreads();

    const int wave = tid >> 6;
    const int lane = tid & 63;
    const int l16  = lane & 15;
    const int lg   = lane >> 4;    // 0..3

    // ---- B-frags: all 128 vectors in registers (8 groups x 2 k-halves)
    bf16x8 bfr[8][2];
#pragma unroll
    for (int g = 0; g < 8; ++g)
#pragma unroll
        for (int h = 0; h < 2; ++h) {
            const int v = g * 16 + l16;
            const int byte = v * 128 + (((h * 64) + lg * 16) ^ ((v & 7) << 4));
            bfr[g][h] = *reinterpret_cast<const bf16x8*>(zl + byte);
        }

    // ---- k-loop over this wave's 256 codes, 16 at a time
    float best[8]; int bidx[8];
#pragma unroll
    for (int g = 0; g < 8; ++g) { best[g] = -3e38f; bidx[g] = 0; }
    const int cw = wave * KPW;
    for (int kt = 0; kt < TILES; ++kt) {
        const int cbase = cw + kt * 16;
        const bf16x8 a0 = *reinterpret_cast<const bf16x8*>(ebf + (size_t)(cbase + l16) * 64 + lg * 8);
        const bf16x8 a1 = *reinterpret_cast<const bf16x8*>(ebf + (size_t)(cbase + l16) * 64 + 32 + lg * 8);
        const float4 h4 = *reinterpret_cast<const float4*>(hn + cbase + lg * 4);
        const float* h4f = reinterpret_cast<const float*>(&h4);
#pragma unroll
        for (int g = 0; g < 8; ++g) {
            f32x4 c = {0.f, 0.f, 0.f, 0.f};
            c = __builtin_amdgcn_mfma_f32_16x16x32_bf16(a0, bfr[g][0], c, 0, 0, 0);
            c = __builtin_amdgcn_mfma_f32_16x16x32_bf16(a1, bfr[g][1], c, 0, 0, 0);
#pragma unroll
            for (int r = 0; r < 4; ++r) {
                const float tv = c[r] - h4f[r];    // z.e - 0.5||e||^2
                if (tv > best[g]) { best[g] = tv; bidx[g] = cbase + lg * 4 + r; }
            }
        }
    }

    // ---- cross-lane argmax (over lg in {0..3}); tie -> lower index
#pragma unroll
    for (int g = 0; g < 8; ++g) {
        float tv = best[g]; int ti = bidx[g];
#pragma unroll
        for (int off = 16; off <= 32; off <<= 1) {
            const float ot = __shfl_xor(tv, off, 64);
            const int   oi = __shfl_xor(ti, off, 64);
            if (ot > tv || (ot == tv && oi < ti)) { tv = ot; ti = oi; }
        }
        if (lg == 0) {
            wv_t[wave * MB + g * 16 + l16] = tv;
            wv_i[wave * MB + g * 16 + l16] = ti;
        }
    }
    __syncthreads();

    // ---- cross-wave combine (threads 0..127); tsum feeds the loss
    float tsum = 0.f;
    if (tid < MB) {
        float tv = wv_t[tid]; int ti = wv_i[tid];
#pragma unroll
        for (int w = 1; w < WAVES; ++w) {
            const float ot = wv_t[w * MB + tid];
            const int   oi = wv_i[w * MB + tid];
            if (ot > tv || (ot == tv && oi < ti)) { tv = ot; ti = oi; }
        }
        fin_i[tid] = ti;
        tsum = tv;
    }
    __syncthreads();

    // ---- output: gather exact f32 code rows, write out[b][d][hw] coalesced
    {
        const int v  = tid & 127;
        const int dh = tid >> 7;              // d-half
        const int idx = fin_i[v];
        const float4* eq4 = reinterpret_cast<const float4*>(emb + (size_t)idx * D);
        float* ob = out + (size_t)b * (D * 1024) + hw0 + v;
#pragma unroll
        for (int i = 0; i < 8; ++i) {
            const float4 q = eq4[dh * 8 + i];
            const int d = dh * 32 + i * 4;
            ob[(size_t)(d + 0) * 1024] = q.x;
            ob[(size_t)(d + 1) * 1024] = q.y;
            ob[(size_t)(d + 2) * 1024] = q.z;
            ob[(size_t)(d + 3) * 1024] = q.w;
        }
    }

    // ---- block reductions: sum(z^2) and sum(t)
    red[tid] = zacc;
    __syncthreads();
#pragma unroll
    for (int s = 128; s > 0; s >>= 1) {
        if (tid < s) red[tid] += red[tid + s];
        __syncthreads();
    }
    if (tid == 0) pZ[blk] = red[0];
    __syncthreads();
    red[tid] = tsum;
    __syncthreads();
#pragma unroll
    for (int s = 128; s > 0; s >>= 1) {
        if (tid < s) red[tid] += red[tid + s];
        __syncthreads();
    }
    if (tid == 0) pT[blk] = red[0];
}

// ---------------------------------------------------------------------------
// Loss: loss = 1.25 * (sum(z^2) - 2*sum(t)) / (NVEC*D)
// ---------------------------------------------------------------------------
__global__ __launch_bounds__(256) void vq_loss(const float* __restrict__ pT,
                                               const float* __restrict__ pZ,
                                               float* __restrict__ loss_out) {
    __shared__ float red[256];
    float s = 0.f;
    for (int i = threadIdx.x; i < NBLK; i += 256) s += pZ[i] - 2.f * pT[i];
    red[threadIdx.x] = s;
    __syncthreads();
#pragma unroll
    for (int st = 128; st > 0; st >>= 1) {
        if (threadIdx.x < st) red[threadIdx.x] += red[threadIdx.x + st];
        __syncthreads();
    }
    if (threadIdx.x == 0)
        loss_out[0] = 1.25f * red[0] * (1.0f / (float)((size_t)NVEC * D));
}

extern "C" void kernel_launch(void* const* d_in, const int* in_sizes, int n_in,
                              void* d_out, int out_size, void* d_ws, size_t ws_size,
                              hipStream_t stream) {
    const float* z   = (const float*)d_in[0];   // [64, 64, 32, 32]
    const float* emb = (const float*)d_in[1];   // [1024, 64]
    float* out = (float*)d_out;                 // 4194304 quantized + 1 loss

    char* ws = (char*)d_ws;
    unsigned short* ebf = (unsigned short*)ws;            // 128 KB
    float* hn = (float*)(ws + 131072);                    // 4 KB
    float* pT = (float*)(ws + 135168);                    // 2 KB
    float* pZ = (float*)(ws + 137216);                    // 2 KB

    vq_prep<<<K / 256, 256, 0, stream>>>(emb, ebf, hn);
    vq_mfma<<<NBLK, 256, 0, stream>>>(z, emb, ebf, hn, out, pT, pZ);
    vq_loss<<<1, 256, 0, stream>>>(pT, pZ, out + (size_t)NVEC * D);
}